// Round 2
// baseline (487.412 us; speedup 1.0000x reference)
//
#include <hip/hip_runtime.h>
#include <hip/hip_bf16.h>

typedef __attribute__((ext_vector_type(8))) short short8;
typedef __attribute__((ext_vector_type(4))) float f32x4;

#define N_NODES 16384
#define FEAT 128
#define NT 256   // K-tiles of 64 in spmm

__device__ __forceinline__ short f2bf(float x) {
  union { float f; unsigned u; } v;
  v.f = x;
  unsigned r = v.u + 0x7fffu + ((v.u >> 16) & 1u);  // RNE; inputs finite
  return (short)(r >> 16);
}

// ---------- Kernel 1: dinv[i] = rsqrt(1 + sum_j adj[i][j]) ----------
__global__ __launch_bounds__(256) void rowsum_kernel(
    const float* __restrict__ adj, float* __restrict__ dinv)
{
  const int row = blockIdx.x;
  const float4* p4 = (const float4*)(adj + (size_t)row * N_NODES);
  float s = 0.f;
  #pragma unroll 4
  for (int i = threadIdx.x; i < N_NODES / 4; i += 256) {
    float4 v = p4[i];
    s += (v.x + v.y) + (v.z + v.w);
  }
  #pragma unroll
  for (int off = 32; off > 0; off >>= 1) s += __shfl_down(s, off, 64);
  __shared__ float part[4];
  if ((threadIdx.x & 63) == 0) part[threadIdx.x >> 6] = s;
  __syncthreads();
  if (threadIdx.x == 0) {
    float tot = (part[0] + part[1]) + (part[2] + part[3]) + 1.0f;
    dinv[row] = rsqrtf(tot);
  }
}

// ---------- Kernel 2: Y[j][f] = d_j * (X@W)[j][f] -> Ynat [j][f] + Ypack [k/8][f][8] ----------
__global__ __launch_bounds__(256) void xw_kernel(
    const float* __restrict__ X, const float* __restrict__ W,
    const float* __restrict__ dinv,
    __hip_bfloat16* __restrict__ Ynat, __hip_bfloat16* __restrict__ Ypack)
{
  __shared__ __align__(16) float Ws[64][128];
  __shared__ __align__(16) float Xs[32][128];
  __shared__ __align__(16) short Ts[128][40];
  const int tid = threadIdx.x;
  const int row0 = blockIdx.x << 5;

  {
    const float4* Xg = (const float4*)(X + ((size_t)row0 << 7));
    float4* Xl = (float4*)&Xs[0][0];
    #pragma unroll
    for (int i = 0; i < 4; ++i) Xl[tid + (i << 8)] = Xg[tid + (i << 8)];
  }
  const int f  = tid & 127;
  const int rr = tid >> 7;
  float acc[16];
  #pragma unroll
  for (int k = 0; k < 16; ++k) acc[k] = 0.f;

  for (int cc = 0; cc < 2; ++cc) {
    __syncthreads();
    {
      const float4* Wg = (const float4*)(W + ((size_t)cc << 13));
      float4* Wl = (float4*)&Ws[0][0];
      #pragma unroll
      for (int i = 0; i < 8; ++i) Wl[tid + (i << 8)] = Wg[tid + (i << 8)];
    }
    __syncthreads();
    for (int c4 = 0; c4 < 16; ++c4) {
      const int cl = c4 << 2;
      const float w0 = Ws[cl + 0][f];
      const float w1 = Ws[cl + 1][f];
      const float w2 = Ws[cl + 2][f];
      const float w3 = Ws[cl + 3][f];
      const int cg = (cc << 6) + cl;
      #pragma unroll
      for (int k = 0; k < 16; ++k) {
        const float4 x = *(const float4*)&Xs[rr + (k << 1)][cg];
        acc[k] += x.x * w0 + x.y * w1 + x.z * w2 + x.w * w3;
      }
    }
  }
  #pragma unroll
  for (int k = 0; k < 16; ++k) {
    const int r = rr + (k << 1);
    const float dv = dinv[row0 + r];
    const short v = f2bf(acc[k] * dv);
    ((short*)Ynat)[(size_t)(row0 + r) * FEAT + f] = v;
    Ts[f][r] = v;
  }
  __syncthreads();
  {
    // Ypack element (f, k) lives at short-offset (k>>3)*1024 + f*8 + (k&7)
    const int f2 = tid >> 1;
    const int h  = (tid & 1) << 4;
    const short8 v0 = *(const short8*)&Ts[f2][h];
    const short8 v1 = *(const short8*)&Ts[f2][h + 8];
    short* o = (short*)Ypack;
    *(short8*)(o + (size_t)(row0 + h) * FEAT + (f2 << 3))     = v0;
    *(short8*)(o + (size_t)(row0 + h + 8) * FEAT + (f2 << 3)) = v1;
  }
}

// ---------- Kernel 3: out = relu(d_i*((A@Y)[i] + Y[i]) + b) ----------
// BM=64, BK=64, 512 thr. A: LDS dbuf + 2-deep reg prefetch. B: direct-global
// fragment loads from Ypack with register ping-pong (counted-vmcnt via deps).
#define SPMM_BODY(T, BCUR, BNXT, ALD0, ALD1, AST0, AST1, RD, WR)               \
  {                                                                            \
    if ((T) + 2 < NT) {  /* A(T+2) -> regs (consumed 2 iters later) */         \
      const float* ap = Ag + (((T) + 2) << 6);                                 \
      ALD0 = *(const float4*)(ap);                                             \
      ALD1 = *(const float4*)(ap + 4);                                         \
    }                                                                          \
    if ((T) + 1 < NT) {  /* B(T+1) frags -> regs (stay in flight across bar) */\
      const short* yp0 = Yg + (((T) + 1) << 13);                               \
      const short* yp1 = yp0 + 4096;                                           \
      BNXT[0] = *(const short8*)(yp0);                                         \
      BNXT[1] = *(const short8*)(yp0 + 128);                                   \
      BNXT[2] = *(const short8*)(yp0 + 256);                                   \
      BNXT[3] = *(const short8*)(yp0 + 384);                                   \
      BNXT[4] = *(const short8*)(yp1);                                         \
      BNXT[5] = *(const short8*)(yp1 + 128);                                   \
      BNXT[6] = *(const short8*)(yp1 + 256);                                   \
      BNXT[7] = *(const short8*)(yp1 + 384);                                   \
    }                                                                          \
    {                                                                          \
      const short8 af0 = *(const short8*)&As[RD][(wm << 4) + lm][lk];          \
      acc[0] = __builtin_amdgcn_mfma_f32_16x16x32_bf16(af0, BCUR[0], acc[0], 0, 0, 0); \
      acc[1] = __builtin_amdgcn_mfma_f32_16x16x32_bf16(af0, BCUR[1], acc[1], 0, 0, 0); \
      acc[2] = __builtin_amdgcn_mfma_f32_16x16x32_bf16(af0, BCUR[2], acc[2], 0, 0, 0); \
      acc[3] = __builtin_amdgcn_mfma_f32_16x16x32_bf16(af0, BCUR[3], acc[3], 0, 0, 0); \
      const short8 af1 = *(const short8*)&As[RD][(wm << 4) + lm][32 + lk];     \
      acc[0] = __builtin_amdgcn_mfma_f32_16x16x32_bf16(af1, BCUR[4], acc[0], 0, 0, 0); \
      acc[1] = __builtin_amdgcn_mfma_f32_16x16x32_bf16(af1, BCUR[5], acc[1], 0, 0, 0); \
      acc[2] = __builtin_amdgcn_mfma_f32_16x16x32_bf16(af1, BCUR[6], acc[2], 0, 0, 0); \
      acc[3] = __builtin_amdgcn_mfma_f32_16x16x32_bf16(af1, BCUR[7], acc[3], 0, 0, 0); \
    }                                                                          \
    if ((T) + 1 < NT) {  /* ds_write A(T+1); its load is 1 body old -> ready */\
      short8 ac;                                                               \
      ac[0] = f2bf(AST0.x); ac[1] = f2bf(AST0.y);                              \
      ac[2] = f2bf(AST0.z); ac[3] = f2bf(AST0.w);                              \
      ac[4] = f2bf(AST1.x); ac[5] = f2bf(AST1.y);                              \
      ac[6] = f2bf(AST1.z); ac[7] = f2bf(AST1.w);                              \
      *(short8*)&As[WR][ar][ak] = ac;                                          \
    }                                                                          \
    __syncthreads();                                                           \
  }

__global__ __launch_bounds__(512, 2) void spmm_kernel(
    const float* __restrict__ A,
    const __hip_bfloat16* __restrict__ Ynat,
    const __hip_bfloat16* __restrict__ Ypack,
    const float* __restrict__ dinv,
    const float* __restrict__ bias,
    float* __restrict__ out)
{
  __shared__ __align__(16) short As[2][64][72];   // 18 KiB only
  const int tid  = threadIdx.x;
  const int row0 = blockIdx.x << 6;

  const int ar = tid >> 3;
  const int ak = (tid & 7) << 3;
  const float* Ag = A + (size_t)(row0 + ar) * N_NODES + ak;

  const int wid  = tid >> 6;
  const int wm   = wid >> 1;        // 0..3: 16-row M-subtile
  const int wf   = wid & 1;         // 0..1: 64-col F-half
  const int lane = tid & 63;
  const int lm   = lane & 15;
  const int lk   = (lane >> 4) << 3;

  // Ypack frag base: (t,ks,c,j) at t*8192 + ks*4096 + lk*128 + wf*512 + c*128 + lm*8 + j
  const short* Yg = (const short*)Ypack + (lk << 7) + (wf << 9) + (lm << 3);

  f32x4 acc[4];
  #pragma unroll
  for (int c = 0; c < 4; ++c) acc[c] = (f32x4){0.f, 0.f, 0.f, 0.f};

  float4 aA0, aA1, aB0, aB1;
  short8 b0[8], b1[8];

  // prologue: A(0)->slotA, A(1)->slotB, B(0)->b0, ds_write A(0)
  aA0 = *(const float4*)(Ag);
  aA1 = *(const float4*)(Ag + 4);
  aB0 = *(const float4*)(Ag + 64);
  aB1 = *(const float4*)(Ag + 68);
  {
    const short* yp0 = Yg;
    const short* yp1 = Yg + 4096;
    b0[0] = *(const short8*)(yp0);
    b0[1] = *(const short8*)(yp0 + 128);
    b0[2] = *(const short8*)(yp0 + 256);
    b0[3] = *(const short8*)(yp0 + 384);
    b0[4] = *(const short8*)(yp1);
    b0[5] = *(const short8*)(yp1 + 128);
    b0[6] = *(const short8*)(yp1 + 256);
    b0[7] = *(const short8*)(yp1 + 384);
  }
  {
    short8 ac;
    ac[0] = f2bf(aA0.x); ac[1] = f2bf(aA0.y); ac[2] = f2bf(aA0.z); ac[3] = f2bf(aA0.w);
    ac[4] = f2bf(aA1.x); ac[5] = f2bf(aA1.y); ac[6] = f2bf(aA1.z); ac[7] = f2bf(aA1.w);
    *(short8*)&As[0][ar][ak] = ac;
  }
  __syncthreads();

  for (int t = 0; t < NT; t += 2) {
    SPMM_BODY(t,     b0, b1, aA0, aA1, aB0, aB1, 0, 1)
    SPMM_BODY(t + 1, b1, b0, aB0, aB1, aA0, aA1, 1, 0)
  }

  // epilogue: out[row][col] = relu(d_row * (acc + Y[row][col]) + b[col])
  const int lr = (lane >> 4) << 2;
  float dreg[4];
  #pragma unroll
  for (int r = 0; r < 4; ++r) dreg[r] = dinv[row0 + (wm << 4) + lr + r];
  #pragma unroll
  for (int c = 0; c < 4; ++c) {
    const int col = (wf << 6) + (c << 4) + lm;
    const float bv = bias[col];
    #pragma unroll
    for (int r = 0; r < 4; ++r) {
      const int row = row0 + (wm << 4) + lr + r;
      const float y = __bfloat162float(Ynat[(size_t)row * FEAT + col]);
      const float v = dreg[r] * (acc[c][r] + y) + bv;
      out[(size_t)row * FEAT + col] = v > 0.f ? v : 0.f;
    }
  }
}

extern "C" void kernel_launch(void* const* d_in, const int* in_sizes, int n_in,
                              void* d_out, int out_size, void* d_ws, size_t ws_size,
                              hipStream_t stream) {
  const float* X   = (const float*)d_in[0];
  const float* adj = (const float*)d_in[1];
  const float* W   = (const float*)d_in[2];
  const float* b   = (const float*)d_in[3];
  float* out = (float*)d_out;

  float* dinv = (float*)d_ws;                                                    // 64 KiB
  __hip_bfloat16* Ynat  = (__hip_bfloat16*)((char*)d_ws + (1 << 16));            // 4 MiB
  __hip_bfloat16* Ypack = (__hip_bfloat16*)((char*)d_ws + (1 << 16) + (1 << 22)); // 4 MiB

  rowsum_kernel<<<N_NODES, 256, 0, stream>>>(adj, dinv);
  xw_kernel<<<N_NODES / 32, 256, 0, stream>>>(X, W, dinv, Ynat, Ypack);
  spmm_kernel<<<N_NODES / 64, 512, 0, stream>>>(adj, Ynat, Ypack, dinv, b, out);
}